// Round 15
// baseline (228.134 us; speedup 1.0000x reference)
//
#include <hip/hip_runtime.h>
#include <cstdint>
#include <cstddef>

#define HWN 16384   // H*W
#define NP1 1024    // pooled positions
#define RL2E 1.44269504f

typedef __attribute__((ext_vector_type(8))) short bf16x8;            // MFMA A/B frag
typedef __attribute__((ext_vector_type(8))) unsigned short ushort8v;
typedef __attribute__((ext_vector_type(4))) unsigned short ushort4v;
typedef __attribute__((ext_vector_type(2))) unsigned int uint2v;
typedef __attribute__((ext_vector_type(4))) unsigned int uint4v;
typedef __attribute__((ext_vector_type(4))) float f32x4;
typedef __attribute__((ext_vector_type(16))) float f32x16;

__device__ __forceinline__ unsigned short f2bu(float f) {
  unsigned int u = __builtin_bit_cast(unsigned int, f);
  u = (u + 0x7FFFu + ((u >> 16) & 1u)) >> 16;   // RNE
  return (unsigned short)u;
}
__device__ __forceinline__ float b2f(unsigned short s) {
  unsigned int u = ((unsigned int)s) << 16;
  return __builtin_bit_cast(float, u);
}
// HW packed f32->bf16 (RNE): D.lo = bf16(S0), D.hi = bf16(S1)
__device__ __forceinline__ unsigned cvtpk(float lo, float hi) {
  unsigned r;
  asm("v_cvt_pk_bf16_f32 %0, %1, %2" : "=v"(r) : "v"(lo), "v"(hi));
  return r;
}
__device__ __forceinline__ bf16x8 scale_l2e(ushort8v t) {   // q-frag prescale by log2(e)
  ushort8v o;
#pragma unroll
  for (int q = 0; q < 8; ++q) o[q] = f2bu(RL2E * b2f(t[q]));
  return __builtin_bit_cast(bf16x8, o);
}
#define MFMA16(A,B,C) __builtin_amdgcn_mfma_f32_16x16x32_bf16((A),(B),(C),0,0,0)
#define MFMA32(A,B,C) __builtin_amdgcn_mfma_f32_32x32x16_bf16((A),(B),(C),0,0,0)
// XOR-swizzled index (ushort units) for 64-col bf16 P tiles: byte ^= (row&7)<<4
#define PIDX(r,c) ((((r) << 6) + (c)) ^ (((r) & 7) << 3))

// ---------------------------------------------------------------------------
// K0: cast+transpose x -> xbT[b][p][c] bf16 ; cast weights -> wqb, wob bf16
// ---------------------------------------------------------------------------
__global__ __launch_bounds__(256) void k_cast(
    const float* __restrict__ x, const float* __restrict__ qkv_w,
    const float* __restrict__ out_w, unsigned short* __restrict__ xbT,
    unsigned short* __restrict__ wqb, unsigned short* __restrict__ wob) {
  int bid = blockIdx.x, t = threadIdx.x;
  if (bid < 2048) {
    __shared__ float Lt[64][65];
    int b = bid >> 10, rest = bid & 1023, ct = rest >> 8, pt = rest & 255;
    const float* xp = x + ((size_t)b * 256 + ct * 64) * HWN + pt * 64;
    for (int it = 0; it < 16; ++it) {
      int idx = it * 256 + t; int cc = idx >> 6, pp = idx & 63;
      Lt[cc][pp] = xp[(size_t)cc * HWN + pp];
    }
    __syncthreads();
    int prow = t >> 2, c0 = (t & 3) * 16;
    unsigned short* dst = xbT + ((size_t)b * HWN + pt * 64 + prow) * 256 + ct * 64 + c0;
    uint4v o1, o2;
#pragma unroll
    for (int q = 0; q < 4; ++q) o1[q] = cvtpk(Lt[c0 + 2*q][prow], Lt[c0 + 2*q + 1][prow]);
#pragma unroll
    for (int q = 0; q < 4; ++q) o2[q] = cvtpk(Lt[c0 + 8 + 2*q][prow], Lt[c0 + 9 + 2*q][prow]);
    *(uint4v*)dst = o1;
    *(uint4v*)(dst + 8) = o2;
  } else {
    int base = (bid - 2048) * 1024 + t * 4;
    if (base < 98304) {
      float4 v = *(const float4*)(qkv_w + base);
      uint2v o; o[0] = cvtpk(v.x, v.y); o[1] = cvtpk(v.z, v.w);
      *(uint2v*)(wqb + base) = o;
    } else {
      int b2 = base - 98304;
      float4 v = *(const float4*)(out_w + b2);
      uint2v o; o[0] = cvtpk(v.x, v.y); o[1] = cvtpk(v.z, v.w);
      *(uint2v*)(wob + b2) = o;
    }
  }
}

// ---------------------------------------------------------------------------
// K1: qkv GEMM, ALL 6 o-tiles (384 rows) per block sharing one B-tile read.
// grid (pt 256, b 2); kT written when ot==1
// ---------------------------------------------------------------------------
__global__ __launch_bounds__(256) void k_qkv(
    const unsigned short* __restrict__ wqb, const unsigned short* __restrict__ xbT,
    const float* __restrict__ qkv_b, unsigned short* __restrict__ qkvb,
    unsigned short* __restrict__ kT) {
  int pt = blockIdx.x, b = blockIdx.y;
  int tid = threadIdx.x, w = tid >> 6, lane = tid & 63;
  int lg = lane >> 4, ln = lane & 15;
  f32x4 acc[6][4] = {};
#pragma unroll
  for (int ks = 0; ks < 8; ++ks) {
    int c0 = ks * 32;
    bf16x8 bx[4];
#pragma unroll
    for (int nt = 0; nt < 4; ++nt)
      bx[nt] = *(const bf16x8*)(xbT + ((size_t)b * HWN + pt * 64 + nt * 16 + ln) * 256 + c0 + lg * 8);
#pragma unroll
    for (int ot = 0; ot < 6; ++ot) {
      bf16x8 aw = *(const bf16x8*)(wqb + (size_t)(ot * 64 + w * 16 + ln) * 256 + c0 + lg * 8);
#pragma unroll
      for (int nt = 0; nt < 4; ++nt)
        acc[ot][nt] = MFMA16(aw, bx[nt], acc[ot][nt]);
    }
  }
#pragma unroll
  for (int ot = 0; ot < 6; ++ot) {
    int ob = ot * 64 + w * 16 + lg * 4;
    float b0 = qkv_b[ob], b1 = qkv_b[ob + 1], b2 = qkv_b[ob + 2], b3 = qkv_b[ob + 3];
#pragma unroll
    for (int nt = 0; nt < 4; ++nt) {
      int p = pt * 64 + nt * 16 + ln;
      unsigned u01 = cvtpk(acc[ot][nt][0] + b0, acc[ot][nt][1] + b1);
      unsigned u23 = cvtpk(acc[ot][nt][2] + b2, acc[ot][nt][3] + b3);
      size_t qb = ((size_t)b * 384 + ob) * HWN + p;
      qkvb[qb]           = (unsigned short)u01;
      qkvb[qb + HWN]     = (unsigned short)(u01 >> 16);
      qkvb[qb + 2 * HWN] = (unsigned short)u23;
      qkvb[qb + 3 * HWN] = (unsigned short)(u23 >> 16);
      if (ot == 1) {   // K channels: g=w>>1, d=(w&1)*16+lg*4
        int bgi = b * 2 + (w >> 1);
        int d0 = (w & 1) * 16 + lg * 4;
        uint2v kv; kv[0] = u01; kv[1] = u23;
        *(uint2v*)(kT + ((size_t)bgi * HWN + p) * 32 + d0) = kv;
      }
    }
  }
}

// ---------------------------------------------------------------------------
// K2: 4x4 avg pool -> qpb[bg][32 d][1024 i] bf16, kpt[bg][1024 i][32 d] bf16
// ---------------------------------------------------------------------------
__global__ __launch_bounds__(256) void k_pool(
    const unsigned short* __restrict__ qkvb, unsigned short* __restrict__ qpb,
    unsigned short* __restrict__ kpt) {
  int idx = blockIdx.x * 256 + threadIdx.x;   // 131072
  int i1 = idx & 1023, cc = (idx >> 10) & 31, bg = idx >> 15;
  int b = bg >> 1, g = bg & 1;
  int h1 = i1 >> 5, w1 = i1 & 31;
  const unsigned short* bq = qkvb + (size_t)(b * 384 + g * 32 + cc) * HWN;
  const unsigned short* bk = qkvb + (size_t)(b * 384 + 64 + g * 32 + cc) * HWN;
  float sq = 0.f, sk = 0.f;
#pragma unroll
  for (int sh = 0; sh < 4; ++sh) {
    int off = (h1 * 4 + sh) * 128 + w1 * 4;
    ushort4v vq = *(const ushort4v*)(bq + off);
    ushort4v vk = *(const ushort4v*)(bk + off);
#pragma unroll
    for (int e = 0; e < 4; ++e) { sq += b2f(vq[e]); sk += b2f(vk[e]); }
  }
  qpb[((size_t)bg * 32 + cc) * NP1 + i1] = f2bu(sq * 0.0625f);
  kpt[((size_t)bg * NP1 + i1) * 32 + cc] = f2bu(sk * 0.0625f);
}

// ---------------------------------------------------------------------------
// K4: MERGED launch: blocks [0,512) = flash W1 (split-K 8, XCD remap, KVB=64,
// register-prefetched pipeline); blocks [512,768) = A_m score kernel.
// ---------------------------------------------------------------------------
__global__ __launch_bounds__(256) void k_fw1s(
    const unsigned short* __restrict__ qkvb, const unsigned short* __restrict__ kT,
    const unsigned short* __restrict__ qpb, const unsigned short* __restrict__ kpt,
    float* __restrict__ pacc, float* __restrict__ pl,
    unsigned short* __restrict__ Eut, float* __restrict__ lpart) {
  __shared__ unsigned short PtS[2][64 * 64];
  __shared__ float redL[4][64];
  int n = blockIdx.x;
  int tid = threadIdx.x, w = tid >> 6, lane = tid & 63;
  int lg = lane >> 4, ln = lane & 15;

  if (n < 512) {
    // ------------------ flash W1 ------------------
    int wid = ((n & 7) << 6) + (n >> 3);
    int jt = wid & 15, kc = (wid >> 4) & 7, bg = wid >> 7;
    int b = bg >> 1, g = bg & 1;
    const int Vch = b * 384 + 128 + g * 128;
    bf16x8 bq[4];
#pragma unroll
    for (int nt = 0; nt < 4; ++nt) {
      ushort8v t8;
#pragma unroll
      for (int jr = 0; jr < 8; ++jr)
        t8[jr] = qpb[((size_t)bg * 32 + lg * 8 + jr) * NP1 + jt * 64 + nt * 16 + ln];
      bq[nt] = scale_l2e(t8);
    }
    f32x4 acc[2][4] = {};
    float lsum[4] = {0.f, 0.f, 0.f, 0.f};
    const int i0base = kc * 2048;
    const unsigned short* kTbase = kT + ((size_t)bg * HWN + i0base + w * 16 + ln) * 32 + lg * 8;
    const unsigned short* Vrow0 = qkvb + (size_t)(Vch + w * 32 + ln) * HWN + i0base + lg * 8;
    const unsigned short* Vrow1 = qkvb + (size_t)(Vch + w * 32 + 16 + ln) * HWN + i0base + lg * 8;

    bf16x8 akA, akB;
    bf16x8 avA[4], avB[4];
    akA = *(const bf16x8*)(kTbase);
    {
      f32x4 sn[4];
#pragma unroll
      for (int nt = 0; nt < 4; ++nt) { f32x4 z = {0.f,0.f,0.f,0.f}; sn[nt] = MFMA16(akA, bq[nt], z); }
      akB = *(const bf16x8*)(kTbase + 2048);
      avA[0] = *(const bf16x8*)(Vrow0);
      avA[1] = *(const bf16x8*)(Vrow1);
      avA[2] = *(const bf16x8*)(Vrow0 + 32);
      avA[3] = *(const bf16x8*)(Vrow1 + 32);
#pragma unroll
      for (int nt = 0; nt < 4; ++nt) {
        float e0 = exp2f(sn[nt][0]), e1 = exp2f(sn[nt][1]), e2 = exp2f(sn[nt][2]), e3 = exp2f(sn[nt][3]);
        lsum[nt] += (e0 + e1) + (e2 + e3);
        uint2v pk; pk[0] = cvtpk(e0, e1); pk[1] = cvtpk(e2, e3);
        *(uint2v*)&PtS[0][PIDX(nt * 16 + ln, w * 16 + lg * 4)] = pk;
      }
    }
    for (int pr = 0; pr < 16; ++pr) {
      int c = pr * 2;
      __syncthreads();
      f32x4 sn[4];
#pragma unroll
      for (int nt = 0; nt < 4; ++nt) { f32x4 z = {0.f,0.f,0.f,0.f}; sn[nt] = MFMA16(akB, bq[nt], z); }
      {
        int c2 = (c + 2) & 31, c1 = c + 1;
        akA = *(const bf16x8*)(kTbase + (size_t)c2 * 2048);
        avB[0] = *(const bf16x8*)(Vrow0 + c1 * 64);
        avB[1] = *(const bf16x8*)(Vrow1 + c1 * 64);
        avB[2] = *(const bf16x8*)(Vrow0 + c1 * 64 + 32);
        avB[3] = *(const bf16x8*)(Vrow1 + c1 * 64 + 32);
      }
      __builtin_amdgcn_s_setprio(1);
#pragma unroll
      for (int ist = 0; ist < 2; ++ist) {
        bf16x8 bp[4];
#pragma unroll
        for (int nt = 0; nt < 4; ++nt)
          bp[nt] = *(const bf16x8*)&PtS[0][PIDX(nt * 16 + ln, ist * 32 + lg * 8)];
#pragma unroll
        for (int nt = 0; nt < 4; ++nt) {
          acc[0][nt] = MFMA16(avA[ist * 2 + 0], bp[nt], acc[0][nt]);
          acc[1][nt] = MFMA16(avA[ist * 2 + 1], bp[nt], acc[1][nt]);
        }
      }
      __builtin_amdgcn_s_setprio(0);
#pragma unroll
      for (int nt = 0; nt < 4; ++nt) {   // pack P(c+1) -> PtS[1]
        float e0 = exp2f(sn[nt][0]), e1 = exp2f(sn[nt][1]), e2 = exp2f(sn[nt][2]), e3 = exp2f(sn[nt][3]);
        lsum[nt] += (e0 + e1) + (e2 + e3);
        uint2v pk; pk[0] = cvtpk(e0, e1); pk[1] = cvtpk(e2, e3);
        *(uint2v*)&PtS[1][PIDX(nt * 16 + ln, w * 16 + lg * 4)] = pk;
      }
      __syncthreads();
      if (pr < 15) {
#pragma unroll
        for (int nt = 0; nt < 4; ++nt) { f32x4 z = {0.f,0.f,0.f,0.f}; sn[nt] = MFMA16(akA, bq[nt], z); }
        int c3 = c + 3, c2 = c + 2;
        akB = *(const bf16x8*)(kTbase + (size_t)c3 * 2048);
        avA[0] = *(const bf16x8*)(Vrow0 + c2 * 64);
        avA[1] = *(const bf16x8*)(Vrow1 + c2 * 64);
        avA[2] = *(const bf16x8*)(Vrow0 + c2 * 64 + 32);
        avA[3] = *(const bf16x8*)(Vrow1 + c2 * 64 + 32);
      }
      __builtin_amdgcn_s_setprio(1);
#pragma unroll
      for (int ist = 0; ist < 2; ++ist) {
        bf16x8 bp[4];
#pragma unroll
        for (int nt = 0; nt < 4; ++nt)
          bp[nt] = *(const bf16x8*)&PtS[1][PIDX(nt * 16 + ln, ist * 32 + lg * 8)];
#pragma unroll
        for (int nt = 0; nt < 4; ++nt) {
          acc[0][nt] = MFMA16(avB[ist * 2 + 0], bp[nt], acc[0][nt]);
          acc[1][nt] = MFMA16(avB[ist * 2 + 1], bp[nt], acc[1][nt]);
        }
      }
      __builtin_amdgcn_s_setprio(0);
      if (pr < 15) {
#pragma unroll
        for (int nt = 0; nt < 4; ++nt) {   // pack P(c+2) -> PtS[0]
          float e0 = exp2f(sn[nt][0]), e1 = exp2f(sn[nt][1]), e2 = exp2f(sn[nt][2]), e3 = exp2f(sn[nt][3]);
          lsum[nt] += (e0 + e1) + (e2 + e3);
          uint2v pk; pk[0] = cvtpk(e0, e1); pk[1] = cvtpk(e2, e3);
          *(uint2v*)&PtS[0][PIDX(nt * 16 + ln, w * 16 + lg * 4)] = pk;
        }
      }
    }
    size_t pb = (((size_t)bg * 16 + jt) * 8 + kc) * 8192;
#pragma unroll
    for (int ct = 0; ct < 2; ++ct)
#pragma unroll
      for (int nt = 0; nt < 4; ++nt)
#pragma unroll
        for (int r = 0; r < 4; ++r)
          pacc[pb + (size_t)(w * 32 + ct * 16 + lg * 4 + r) * 64 + nt * 16 + ln] = acc[ct][nt][r];
#pragma unroll
    for (int nt = 0; nt < 4; ++nt) {
      float v = lsum[nt];
      v += __shfl_xor(v, 16); v += __shfl_xor(v, 32);
      if (lane < 16) redL[w][nt * 16 + lane] = v;
    }
    __syncthreads();
    if (tid < 64)
      pl[(((size_t)bg * 16 + jt) * 8 + kc) * 64 + tid] =
          redL[0][tid] + redL[1][tid] + redL[2][tid] + redL[3][tid];
  } else {
    // ------------------ A_m scores (Eut, lpart) ------------------
    int n2 = n - 512;
    int jt = n2 & 15, ic = (n2 >> 4) & 3, bg = n2 >> 6;
    bf16x8 bq[4];
#pragma unroll
    for (int nt = 0; nt < 4; ++nt) {
      ushort8v t8;
#pragma unroll
      for (int jr = 0; jr < 8; ++jr)
        t8[jr] = qpb[((size_t)bg * 32 + lg * 8 + jr) * NP1 + jt * 64 + nt * 16 + ln];
      bq[nt] = scale_l2e(t8);
    }
    float lsum[4] = {0.f, 0.f, 0.f, 0.f};
    for (int chk = 0; chk < 4; ++chk) {
      int i0 = ic * 256 + chk * 64;
      bf16x8 ak = *(const bf16x8*)(kpt + ((size_t)bg * NP1 + i0 + w * 16 + ln) * 32 + lg * 8);
#pragma unroll
      for (int nt = 0; nt < 4; ++nt) {
        f32x4 z = {0.f, 0.f, 0.f, 0.f};
        f32x4 s = MFMA16(ak, bq[nt], z);
        float e0 = exp2f(s[0]), e1 = exp2f(s[1]), e2 = exp2f(s[2]), e3 = exp2f(s[3]);
        lsum[nt] += (e0 + e1) + (e2 + e3);
        int j = jt * 64 + nt * 16 + ln;
        int ib = i0 + w * 16 + lg * 4;
        uint2v pk;
        pk[0] = cvtpk(e0, e1);
        pk[1] = cvtpk(e2, e3);
        *(uint2v*)(Eut + ((size_t)bg * NP1 + j) * NP1 + ib) = pk;
      }
    }
#pragma unroll
    for (int nt = 0; nt < 4; ++nt) {
      float v = lsum[nt];
      v += __shfl_xor(v, 16); v += __shfl_xor(v, 32);
      if (lane < 16) redL[w][nt * 16 + lane] = v;
    }
    __syncthreads();
    if (tid < 64)
      lpart[((size_t)(bg * 4 + ic)) * NP1 + jt * 64 + tid] =
          redL[0][tid] + redL[1][tid] + redL[2][tid] + redL[3][tid];
  }
}

// ---------------------------------------------------------------------------
// K5: MERGED: blocks [0,2048) = split-K combine -> Yf; blocks [2048,2176) =
// rvec partials (row-parallel) + linv.
// ---------------------------------------------------------------------------
__global__ __launch_bounds__(256) void k_comb2(
    const float* __restrict__ pacc, const float* __restrict__ pl,
    float* __restrict__ Yf, const unsigned short* __restrict__ Eut,
    const float* __restrict__ lpart, float* __restrict__ linv,
    float* __restrict__ rvecp) {
  int n = blockIdx.x, t = threadIdx.x;
  if (n < 2048) {
    int gid = n * 256 + t;   // 524288
    int bg = gid >> 17, rem = gid & 131071;
    int c = rem >> 10, j = rem & 1023;
    int jt = j >> 6, jj = j & 63;
    float s = 0.f, l = 0.f;
#pragma unroll
    for (int kc = 0; kc < 8; ++kc) {
      size_t pb = ((size_t)bg * 16 + jt) * 8 + kc;
      s += pacc[pb * 8192 + c * 64 + jj];
      l += pl[pb * 64 + jj];
    }
    Yf[gid] = s / l;
  } else {
    __shared__ float linv_s[32];
    int n2 = n - 2048;
    int jc = n2 & 31, bg = n2 >> 5;
    if (t < 32) {
      int j = jc * 32 + t;
      float l = lpart[((size_t)(bg * 4 + 0)) * NP1 + j] + lpart[((size_t)(bg * 4 + 1)) * NP1 + j] +
                lpart[((size_t)(bg * 4 + 2)) * NP1 + j] + lpart[((size_t)(bg * 4 + 3)) * NP1 + j];
      float inv = 1.f / l;
      linv_s[t] = inv;
      linv[(size_t)bg * NP1 + j] = inv;
    }
    __syncthreads();
    int i0 = t * 4;
    float a0 = 0.f, a1 = 0.f, a2 = 0.f, a3 = 0.f;
#pragma unroll 8
    for (int jj = 0; jj < 32; ++jj) {
      float li = linv_s[jj];
      ushort4v e4 = *(const ushort4v*)(Eut + ((size_t)bg * NP1 + jc * 32 + jj) * NP1 + i0);
      a0 += b2f(e4[0]) * li; a1 += b2f(e4[1]) * li;
      a2 += b2f(e4[2]) * li; a3 += b2f(e4[3]) * li;
    }
    float4 o = {a0, a1, a2, a3};
    *(float4*)(rvecp + ((size_t)(jc * 4 + bg)) * NP1 + i0) = o;
  }
}

// ---------------------------------------------------------------------------
// K5b: Perron deflation: c_row=(y.r)/(1.r); Yf := Y-c/2, U0b := bf16(Y-c).
// grid (ct 16, bg 4)
// ---------------------------------------------------------------------------
__global__ __launch_bounds__(256) void k_proj(
    const float* __restrict__ rvecp, float* __restrict__ Yf,
    unsigned short* __restrict__ U0b) {
  int ct = blockIdx.x, bg = blockIdx.y, t = threadIdx.x;
  __shared__ float rs[1024];
  __shared__ float red[256];
  __shared__ float crow[8];
  __shared__ float sSs;
  for (int j = t; j < 1024; j += 256) {
    float s = 0.f;
#pragma unroll
    for (int p = 0; p < 32; ++p) s += rvecp[((size_t)(p * 4 + bg)) * NP1 + j];
    rs[j] = s;
  }
  __syncthreads();
  float p = rs[t] + rs[t + 256] + rs[t + 512] + rs[t + 768];
  red[t] = p; __syncthreads();
  for (int s = 128; s > 0; s >>= 1) {
    if (t < s) red[t] += red[t + s];
    __syncthreads();
  }
  if (t == 0) sSs = red[0];
  __syncthreads();
  int row = t >> 5, ln32 = t & 31;
  const float* yrow = Yf + ((size_t)(bg * 128 + ct * 8 + row)) * NP1;
  float a = 0.f;
  for (int j = ln32; j < 1024; j += 32) a += yrow[j] * rs[j];
#pragma unroll
  for (int m = 1; m <= 16; m <<= 1) a += __shfl_xor(a, m, 32);
  if (ln32 == 0) crow[row] = a / sSs;
  __syncthreads();
  for (int e = t; e < 8 * 1024; e += 256) {
    int rr = e >> 10, j = e & 1023;
    size_t o = ((size_t)(bg * 128 + ct * 8 + rr)) * NP1 + j;
    float y = Yf[o], cv = crow[rr];
    Yf[o] = y - 0.5f * cv;
    U0b[o] = f2bu(y - cv);
  }
}

// ---------------------------------------------------------------------------
// K6: single Neumann step: W2b = bf16(Yf - (U0 . Eut)*linv[j])
// grid (jt 32, ct 2, bg 4)
// ---------------------------------------------------------------------------
__global__ __launch_bounds__(256) void k_neu(
    const unsigned short* __restrict__ Vin, const unsigned short* __restrict__ Eut,
    const float* __restrict__ linv, const float* __restrict__ W2f,
    unsigned short* __restrict__ W2b) {
  int jt = blockIdx.x, ct = blockIdx.y, bg = blockIdx.z;
  int tid = threadIdx.x, w = tid >> 6, lane = tid & 63;
  int lg = lane >> 4, ln = lane & 15;
  int j0 = jt * 32, c0 = ct * 64 + w * 16;
  f32x4 acc[2] = {};
  for (int ks = 0; ks < 32; ++ks) {
    int i0 = ks * 32;
    bf16x8 a = *(const bf16x8*)(Vin + ((size_t)(bg * 128) + c0 + ln) * NP1 + i0 + lg * 8);
#pragma unroll
    for (int nt = 0; nt < 2; ++nt) {
      bf16x8 bt = *(const bf16x8*)(Eut + ((size_t)bg * NP1 + j0 + nt * 16 + ln) * NP1 + i0 + lg * 8);
      acc[nt] = MFMA16(a, bt, acc[nt]);
    }
  }
#pragma unroll
  for (int nt = 0; nt < 2; ++nt) {
    int j = j0 + nt * 16 + ln;
    float li = linv[(size_t)bg * NP1 + j];
#pragma unroll
    for (int r = 0; r < 4; ++r) {
      size_t o = ((size_t)(bg * 128) + c0 + lg * 4 + r) * NP1 + j;
      W2b[o] = f2bu(W2f[o] - acc[nt][r] * li);
    }
  }
}

// ---------------------------------------------------------------------------
// K7: flash O = W2 @ exp(k^T Qf)/l + W2[:,i1(j)]   (full M^-1 in W2)
// 32x32 swapped-operand form: lane holds P-row for its query; cross-lane
// exchange via shfl_xor(32) only; ZERO barriers / LDS tiles in main loop.
// grid (jt 512, bg 4), 64 threads = 1 wave, 32 queries/wave.
// ---------------------------------------------------------------------------
__global__ __launch_bounds__(64) void k_flashO(
    const unsigned short* __restrict__ qkvb, const unsigned short* __restrict__ kpt,
    const unsigned short* __restrict__ W2b, unsigned short* __restrict__ Ot) {
  int jt = blockIdx.x, bg = blockIdx.y;
  int b = bg >> 1, g = bg & 1;
  int lane = threadIdx.x;
  int q32 = lane & 31, hi = lane >> 5;
  __shared__ float sL[32];
  const int Qch = b * 384 + g * 32;
  const int qglob = jt * 32 + q32;
  // Q B-frags: bq[win] holds Q[d=win*16+hi*8+j][qglob], prescaled by log2e
  bf16x8 bq[2];
#pragma unroll
  for (int win = 0; win < 2; ++win) {
    ushort8v t8;
#pragma unroll
    for (int j = 0; j < 8; ++j)
      t8[j] = qkvb[(size_t)(Qch + win * 16 + hi * 8 + j) * HWN + qglob];
    bq[win] = scale_l2e(t8);
  }
  f32x16 acc[4] = {};   // 4 channel tiles of 32; row=query(r,hi), col=channel q32
  float lsum = 0.f;
  const unsigned short* kb = kpt + (size_t)bg * NP1 * 32;
  const unsigned short* Wb = W2b + (size_t)bg * 128 * NP1;
  const f32x16 zz = {};
  for (int i0 = 0; i0 < 1024; i0 += 32) {
    // scores: S = K·Q  (M=keys 32, N=queries 32, K=d 16 x2)
    bf16x8 ak0 = *(const bf16x8*)(kb + (size_t)(i0 + q32) * 32 + hi * 8);
    bf16x8 ak1 = *(const bf16x8*)(kb + (size_t)(i0 + q32) * 32 + 16 + hi * 8);
    f32x16 s = MFMA32(ak0, bq[0], zz);
    s = MFMA32(ak1, bq[1], s);
    // exp (rows r -> key (r&3)+8*(r>>2)+4*hi of this 32-key set; col = my query)
    float p[16];
#pragma unroll
    for (int r = 0; r < 16; ++r) p[r] = exp2f(s[r]);
#pragma unroll
    for (int r = 0; r < 16; ++r) lsum += p[r];
    unsigned d[8], sw[8];
#pragma unroll
    for (int m = 0; m < 8; ++m) d[m] = cvtpk(p[2 * m], p[2 * m + 1]);
#pragma unroll
    for (int m = 0; m < 8; ++m) sw[m] = (unsigned)__shfl_xor((int)d[m], 32);
    // assemble PV A-frags (k = win*16 + hi*8 + j, j ascending)
    uint4v w0, w1;
    w0[0] = hi ? sw[2] : d[0];
    w0[1] = hi ? sw[3] : d[1];
    w0[2] = hi ? d[2] : sw[0];
    w0[3] = hi ? d[3] : sw[1];
    w1[0] = hi ? sw[6] : d[4];
    w1[1] = hi ? sw[7] : d[5];
    w1[2] = hi ? d[6] : sw[4];
    w1[3] = hi ? d[7] : sw[5];
    bf16x8 pa0 = __builtin_bit_cast(bf16x8, w0);
    bf16x8 pa1 = __builtin_bit_cast(bf16x8, w1);
    // PV: O[q][c] += P·W2^T ; B rows = channels, k = keys
#pragma unroll
    for (int ct = 0; ct < 4; ++ct) {
      const unsigned short* wr = Wb + (size_t)(ct * 32 + q32) * NP1 + i0;
      bf16x8 bv0 = *(const bf16x8*)(wr + hi * 8);
      bf16x8 bv1 = *(const bf16x8*)(wr + 16 + hi * 8);
      acc[ct] = MFMA32(pa0, bv0, acc[ct]);
      acc[ct] = MFMA32(pa1, bv1, acc[ct]);
    }
  }
  lsum += __shfl_xor(lsum, 32);
  sL[q32] = lsum;   // both hi halves write identical value
  __syncthreads();
#pragma unroll
  for (int ct = 0; ct < 4; ++ct) {
    int chl = ct * 32 + q32;           // bg-local channel
    int chg = g * 128 + chl;           // global channel
#pragma unroll
    for (int r = 0; r < 16; ++r) {
      int qrow = (r & 3) + 8 * (r >> 2) + 4 * hi;
      int qg = jt * 32 + qrow;
      float li = 1.f / sL[qrow];
      int i1 = (qg >> 9) * 32 + ((qg & 127) >> 2);
      float v = acc[ct][r] * li + b2f(W2b[((size_t)bg * 128 + chl) * NP1 + i1]);
      Ot[((size_t)b * HWN + qg) * 256 + chg] = f2bu(v);
    }
  }
}

// ---------------------------------------------------------------------------
// K8: out GEMM, ALL 4 o-tiles (256 rows) per block; residual from xbT (bf16).
// grid (pt 256, b 2)
// ---------------------------------------------------------------------------
__global__ __launch_bounds__(256) void k_out(
    const unsigned short* __restrict__ wob, const unsigned short* __restrict__ Ot,
    const float* __restrict__ out_b, const unsigned short* __restrict__ xbT,
    const float* __restrict__ gamma, const int* __restrict__ mode,
    float* __restrict__ out) {
  int pt = blockIdx.x, b = blockIdx.y;
  int tid = threadIdx.x, w = tid >> 6, lane = tid & 63;
  int lg = lane >> 4, ln = lane & 15;
  f32x4 acc[4][4] = {};
#pragma unroll
  for (int ks = 0; ks < 8; ++ks) {
    int c0 = ks * 32;
    bf16x8 bx[4];
#pragma unroll
    for (int nt = 0; nt < 4; ++nt)
      bx[nt] = *(const bf16x8*)(Ot + ((size_t)b * HWN + pt * 64 + nt * 16 + ln) * 256 + c0 + lg * 8);
#pragma unroll
    for (int h = 0; h < 4; ++h) {
      bf16x8 aw = *(const bf16x8*)(wob + (size_t)(h * 64 + w * 16 + ln) * 256 + c0 + lg * 8);
#pragma unroll
      for (int nt = 0; nt < 4; ++nt)
        acc[h][nt] = MFMA16(aw, bx[nt], acc[h][nt]);
    }
  }
  float gm = gamma[0];
  int md = mode[0];
#pragma unroll
  for (int h = 0; h < 4; ++h) {
    int o0 = h * 64 + w * 16 + lg * 4;
    float b0 = out_b[o0], b1 = out_b[o0 + 1], b2 = out_b[o0 + 2], b3 = out_b[o0 + 3];
#pragma unroll
    for (int nt = 0; nt < 4; ++nt) {
      int p = pt * 64 + nt * 16 + ln;
      ushort4v xr = *(const ushort4v*)(xbT + ((size_t)b * HWN + p) * 256 + o0);
      float v0 = acc[h][nt][0] + b0, v1 = acc[h][nt][1] + b1;
      float v2 = acc[h][nt][2] + b2, v3 = acc[h][nt][3] + b3;
      size_t off = ((size_t)b * 256 + o0) * HWN + p;
      if (md == 0) {
        out[off]           = gm * v0 + b2f(xr[0]);
        out[off + HWN]     = gm * v1 + b2f(xr[1]);
        out[off + 2 * HWN] = gm * v2 + b2f(xr[2]);
        out[off + 3 * HWN] = gm * v3 + b2f(xr[3]);
      } else {
        out[off]           = v0;
        out[off + HWN]     = v1;
        out[off + 2 * HWN] = v2;
        out[off + 3 * HWN] = v3;
      }
    }
  }
}

// ---------------------------------------------------------------------------
extern "C" void kernel_launch(void* const* d_in, const int* in_sizes, int n_in,
                              void* d_out, int out_size, void* d_ws, size_t ws_size,
                              hipStream_t stream) {
  (void)in_sizes; (void)n_in; (void)out_size;
  const float* x     = (const float*)d_in[0];
  const float* qkv_w = (const float*)d_in[1];
  const float* qkv_b = (const float*)d_in[2];
  const float* out_w = (const float*)d_in[3];
  const float* out_b = (const float*)d_in[4];
  const float* gamma = (const float*)d_in[5];
  const int*   mode  = (const int*)d_in[6];
  float* out = (float*)d_out;

  char* wsb = (char*)d_ws;
  size_t off = 0;
  auto alloc = [&](size_t bytes) { char* p = wsb + off; off += bytes; return p; };
  unsigned short* xbT  = (unsigned short*)alloc(16777216);  // [2][16384][256]
  unsigned short* wqb  = (unsigned short*)alloc(196608);
  unsigned short* wob  = (unsigned short*)alloc(131072);
  unsigned short* qkvb = (unsigned short*)alloc(25165824);  // [2][384][16384]
  unsigned short* kT   = (unsigned short*)alloc(4194304);   // [4][16384][32]
  unsigned short* qpb  = (unsigned short*)alloc(262144);    // [4][32][1024]
  unsigned short* kpt  = (unsigned short*)alloc(262144);    // [4][1024][32]
  unsigned short* Eut  = (unsigned short*)alloc(8388608);   // [4][1024 j][1024 i]
  float*          lpart= (float*)alloc(65536);              // [4][4][1024]
  float*          linv = (float*)alloc(16384);              // [4][1024]
  float*          rvecp= (float*)alloc(524288);             // [32][4][1024]
  float*          pacc = (float*)alloc(16777216);           // [4][16][8][128][64]
  float*          pl   = (float*)alloc(131072);             // [4][16][8][64]
  float*          Yf   = (float*)alloc(2097152);            // [4][128][1024]
  unsigned short* U0b  = (unsigned short*)alloc(1048576);
  unsigned short* W2b  = (unsigned short*)alloc(1048576);
  unsigned short* Ot   = (unsigned short*)pacc;             // alias: pacc dead after k_comb2
  if (ws_size < off) return;   // ~76.5 MB

  k_cast<<<2208, 256, 0, stream>>>(x, qkv_w, out_w, xbT, wqb, wob);
  k_qkv<<<dim3(256, 2), 256, 0, stream>>>(wqb, xbT, qkv_b, qkvb, kT);
  k_pool<<<512, 256, 0, stream>>>(qkvb, qpb, kpt);
  k_fw1s<<<768, 256, 0, stream>>>(qkvb, kT, qpb, kpt, pacc, pl, Eut, lpart);
  k_comb2<<<2176, 256, 0, stream>>>(pacc, pl, Yf, Eut, lpart, linv, rvecp);
  k_proj<<<dim3(16, 4), 256, 0, stream>>>(rvecp, Yf, U0b);
  k_neu<<<dim3(32, 2, 4), 256, 0, stream>>>(U0b, Eut, linv, Yf, W2b);
  k_flashO<<<dim3(512, 4), 64, 0, stream>>>(qkvb, kpt, W2b, Ot);
  k_out<<<dim3(256, 2), 256, 0, stream>>>(wob, Ot, out_b, xbT, gamma, mode, out);
}

// Round 17
// 187.759 us; speedup vs baseline: 1.2150x; 1.2150x over previous
//
#include <hip/hip_runtime.h>
#include <cstdint>
#include <cstddef>

#define HWN 16384   // H*W
#define NP1 1024    // pooled positions
#define RL2E 1.44269504f

typedef __attribute__((ext_vector_type(8))) short bf16x8;            // MFMA A/B frag
typedef __attribute__((ext_vector_type(8))) unsigned short ushort8v;
typedef __attribute__((ext_vector_type(4))) unsigned short ushort4v;
typedef __attribute__((ext_vector_type(2))) unsigned int uint2v;
typedef __attribute__((ext_vector_type(4))) unsigned int uint4v;
typedef __attribute__((ext_vector_type(4))) float f32x4;

__device__ __forceinline__ unsigned short f2bu(float f) {
  unsigned int u = __builtin_bit_cast(unsigned int, f);
  u = (u + 0x7FFFu + ((u >> 16) & 1u)) >> 16;   // RNE
  return (unsigned short)u;
}
__device__ __forceinline__ float b2f(unsigned short s) {
  unsigned int u = ((unsigned int)s) << 16;
  return __builtin_bit_cast(float, u);
}
// HW packed f32->bf16 (RNE): D.lo = bf16(S0), D.hi = bf16(S1)
__device__ __forceinline__ unsigned cvtpk(float lo, float hi) {
  unsigned r;
  asm("v_cvt_pk_bf16_f32 %0, %1, %2" : "=v"(r) : "v"(lo), "v"(hi));
  return r;
}
__device__ __forceinline__ bf16x8 scale_l2e(ushort8v t) {   // q-frag prescale by log2(e)
  ushort8v o;
#pragma unroll
  for (int q = 0; q < 8; ++q) o[q] = f2bu(RL2E * b2f(t[q]));
  return __builtin_bit_cast(bf16x8, o);
}
#define MFMA16(A,B,C) __builtin_amdgcn_mfma_f32_16x16x32_bf16((A),(B),(C),0,0,0)
// XOR-swizzled index (ushort units) for 64-col bf16 P tiles: byte ^= (row&7)<<4
#define PIDX(r,c) ((((r) << 6) + (c)) ^ (((r) & 7) << 3))

// ---------------------------------------------------------------------------
// K0: cast+transpose x -> xbT[b][p][c] bf16 ; cast weights -> wqb, wob bf16
// ---------------------------------------------------------------------------
__global__ __launch_bounds__(256) void k_cast(
    const float* __restrict__ x, const float* __restrict__ qkv_w,
    const float* __restrict__ out_w, unsigned short* __restrict__ xbT,
    unsigned short* __restrict__ wqb, unsigned short* __restrict__ wob) {
  int bid = blockIdx.x, t = threadIdx.x;
  if (bid < 2048) {
    __shared__ float Lt[64][65];
    int b = bid >> 10, rest = bid & 1023, ct = rest >> 8, pt = rest & 255;
    const float* xp = x + ((size_t)b * 256 + ct * 64) * HWN + pt * 64;
    for (int it = 0; it < 16; ++it) {
      int idx = it * 256 + t; int cc = idx >> 6, pp = idx & 63;
      Lt[cc][pp] = xp[(size_t)cc * HWN + pp];
    }
    __syncthreads();
    int prow = t >> 2, c0 = (t & 3) * 16;
    unsigned short* dst = xbT + ((size_t)b * HWN + pt * 64 + prow) * 256 + ct * 64 + c0;
    uint4v o1, o2;
#pragma unroll
    for (int q = 0; q < 4; ++q) o1[q] = cvtpk(Lt[c0 + 2*q][prow], Lt[c0 + 2*q + 1][prow]);
#pragma unroll
    for (int q = 0; q < 4; ++q) o2[q] = cvtpk(Lt[c0 + 8 + 2*q][prow], Lt[c0 + 9 + 2*q][prow]);
    *(uint4v*)dst = o1;
    *(uint4v*)(dst + 8) = o2;
  } else {
    int base = (bid - 2048) * 1024 + t * 4;
    if (base < 98304) {
      float4 v = *(const float4*)(qkv_w + base);
      uint2v o; o[0] = cvtpk(v.x, v.y); o[1] = cvtpk(v.z, v.w);
      *(uint2v*)(wqb + base) = o;
    } else {
      int b2 = base - 98304;
      float4 v = *(const float4*)(out_w + b2);
      uint2v o; o[0] = cvtpk(v.x, v.y); o[1] = cvtpk(v.z, v.w);
      *(uint2v*)(wob + b2) = o;
    }
  }
}

// ---------------------------------------------------------------------------
// K1: qkv GEMM, ALL 6 o-tiles (384 rows) per block sharing one B-tile read.
// grid (pt 256, b 2); kT written when ot==1
// ---------------------------------------------------------------------------
__global__ __launch_bounds__(256) void k_qkv(
    const unsigned short* __restrict__ wqb, const unsigned short* __restrict__ xbT,
    const float* __restrict__ qkv_b, unsigned short* __restrict__ qkvb,
    unsigned short* __restrict__ kT) {
  int pt = blockIdx.x, b = blockIdx.y;
  int tid = threadIdx.x, w = tid >> 6, lane = tid & 63;
  int lg = lane >> 4, ln = lane & 15;
  f32x4 acc[6][4] = {};
#pragma unroll
  for (int ks = 0; ks < 8; ++ks) {
    int c0 = ks * 32;
    bf16x8 bx[4];
#pragma unroll
    for (int nt = 0; nt < 4; ++nt)
      bx[nt] = *(const bf16x8*)(xbT + ((size_t)b * HWN + pt * 64 + nt * 16 + ln) * 256 + c0 + lg * 8);
#pragma unroll
    for (int ot = 0; ot < 6; ++ot) {
      bf16x8 aw = *(const bf16x8*)(wqb + (size_t)(ot * 64 + w * 16 + ln) * 256 + c0 + lg * 8);
#pragma unroll
      for (int nt = 0; nt < 4; ++nt)
        acc[ot][nt] = MFMA16(aw, bx[nt], acc[ot][nt]);
    }
  }
#pragma unroll
  for (int ot = 0; ot < 6; ++ot) {
    int ob = ot * 64 + w * 16 + lg * 4;
    float b0 = qkv_b[ob], b1 = qkv_b[ob + 1], b2 = qkv_b[ob + 2], b3 = qkv_b[ob + 3];
#pragma unroll
    for (int nt = 0; nt < 4; ++nt) {
      int p = pt * 64 + nt * 16 + ln;
      unsigned u01 = cvtpk(acc[ot][nt][0] + b0, acc[ot][nt][1] + b1);
      unsigned u23 = cvtpk(acc[ot][nt][2] + b2, acc[ot][nt][3] + b3);
      size_t qb = ((size_t)b * 384 + ob) * HWN + p;
      qkvb[qb]           = (unsigned short)u01;
      qkvb[qb + HWN]     = (unsigned short)(u01 >> 16);
      qkvb[qb + 2 * HWN] = (unsigned short)u23;
      qkvb[qb + 3 * HWN] = (unsigned short)(u23 >> 16);
      if (ot == 1) {   // K channels: g=w>>1, d=(w&1)*16+lg*4
        int bgi = b * 2 + (w >> 1);
        int d0 = (w & 1) * 16 + lg * 4;
        uint2v kv; kv[0] = u01; kv[1] = u23;
        *(uint2v*)(kT + ((size_t)bgi * HWN + p) * 32 + d0) = kv;
      }
    }
  }
}

// ---------------------------------------------------------------------------
// K2: 4x4 avg pool -> qpb[bg][32 d][1024 i] bf16, kpt[bg][1024 i][32 d] bf16
// ---------------------------------------------------------------------------
__global__ __launch_bounds__(256) void k_pool(
    const unsigned short* __restrict__ qkvb, unsigned short* __restrict__ qpb,
    unsigned short* __restrict__ kpt) {
  int idx = blockIdx.x * 256 + threadIdx.x;   // 131072
  int i1 = idx & 1023, cc = (idx >> 10) & 31, bg = idx >> 15;
  int b = bg >> 1, g = bg & 1;
  int h1 = i1 >> 5, w1 = i1 & 31;
  const unsigned short* bq = qkvb + (size_t)(b * 384 + g * 32 + cc) * HWN;
  const unsigned short* bk = qkvb + (size_t)(b * 384 + 64 + g * 32 + cc) * HWN;
  float sq = 0.f, sk = 0.f;
#pragma unroll
  for (int sh = 0; sh < 4; ++sh) {
    int off = (h1 * 4 + sh) * 128 + w1 * 4;
    ushort4v vq = *(const ushort4v*)(bq + off);
    ushort4v vk = *(const ushort4v*)(bk + off);
#pragma unroll
    for (int e = 0; e < 4; ++e) { sq += b2f(vq[e]); sk += b2f(vk[e]); }
  }
  qpb[((size_t)bg * 32 + cc) * NP1 + i1] = f2bu(sq * 0.0625f);
  kpt[((size_t)bg * NP1 + i1) * 32 + cc] = f2bu(sk * 0.0625f);
}

// ---------------------------------------------------------------------------
// K4: MERGED launch: blocks [0,512) = flash W1 (split-K 8, XCD remap, KVB=64,
// register-prefetched pipeline); blocks [512,768) = A_m score kernel.
// ---------------------------------------------------------------------------
__global__ __launch_bounds__(256) void k_fw1s(
    const unsigned short* __restrict__ qkvb, const unsigned short* __restrict__ kT,
    const unsigned short* __restrict__ qpb, const unsigned short* __restrict__ kpt,
    float* __restrict__ pacc, float* __restrict__ pl,
    unsigned short* __restrict__ Eut, float* __restrict__ lpart) {
  __shared__ unsigned short PtS[2][64 * 64];
  __shared__ float redL[4][64];
  int n = blockIdx.x;
  int tid = threadIdx.x, w = tid >> 6, lane = tid & 63;
  int lg = lane >> 4, ln = lane & 15;

  if (n < 512) {
    // ------------------ flash W1 ------------------
    int wid = ((n & 7) << 6) + (n >> 3);
    int jt = wid & 15, kc = (wid >> 4) & 7, bg = wid >> 7;
    int b = bg >> 1, g = bg & 1;
    const int Vch = b * 384 + 128 + g * 128;
    bf16x8 bq[4];
#pragma unroll
    for (int nt = 0; nt < 4; ++nt) {
      ushort8v t8;
#pragma unroll
      for (int jr = 0; jr < 8; ++jr)
        t8[jr] = qpb[((size_t)bg * 32 + lg * 8 + jr) * NP1 + jt * 64 + nt * 16 + ln];
      bq[nt] = scale_l2e(t8);
    }
    f32x4 acc[2][4] = {};
    float lsum[4] = {0.f, 0.f, 0.f, 0.f};
    const int i0base = kc * 2048;
    const unsigned short* kTbase = kT + ((size_t)bg * HWN + i0base + w * 16 + ln) * 32 + lg * 8;
    const unsigned short* Vrow0 = qkvb + (size_t)(Vch + w * 32 + ln) * HWN + i0base + lg * 8;
    const unsigned short* Vrow1 = qkvb + (size_t)(Vch + w * 32 + 16 + ln) * HWN + i0base + lg * 8;

    bf16x8 akA, akB;
    bf16x8 avA[4], avB[4];
    akA = *(const bf16x8*)(kTbase);
    {
      f32x4 sn[4];
#pragma unroll
      for (int nt = 0; nt < 4; ++nt) { f32x4 z = {0.f,0.f,0.f,0.f}; sn[nt] = MFMA16(akA, bq[nt], z); }
      akB = *(const bf16x8*)(kTbase + 2048);
      avA[0] = *(const bf16x8*)(Vrow0);
      avA[1] = *(const bf16x8*)(Vrow1);
      avA[2] = *(const bf16x8*)(Vrow0 + 32);
      avA[3] = *(const bf16x8*)(Vrow1 + 32);
#pragma unroll
      for (int nt = 0; nt < 4; ++nt) {
        float e0 = exp2f(sn[nt][0]), e1 = exp2f(sn[nt][1]), e2 = exp2f(sn[nt][2]), e3 = exp2f(sn[nt][3]);
        lsum[nt] += (e0 + e1) + (e2 + e3);
        uint2v pk; pk[0] = cvtpk(e0, e1); pk[1] = cvtpk(e2, e3);
        *(uint2v*)&PtS[0][PIDX(nt * 16 + ln, w * 16 + lg * 4)] = pk;
      }
    }
    for (int pr = 0; pr < 16; ++pr) {
      int c = pr * 2;
      __syncthreads();
      f32x4 sn[4];
#pragma unroll
      for (int nt = 0; nt < 4; ++nt) { f32x4 z = {0.f,0.f,0.f,0.f}; sn[nt] = MFMA16(akB, bq[nt], z); }
      {
        int c2 = (c + 2) & 31, c1 = c + 1;
        akA = *(const bf16x8*)(kTbase + (size_t)c2 * 2048);
        avB[0] = *(const bf16x8*)(Vrow0 + c1 * 64);
        avB[1] = *(const bf16x8*)(Vrow1 + c1 * 64);
        avB[2] = *(const bf16x8*)(Vrow0 + c1 * 64 + 32);
        avB[3] = *(const bf16x8*)(Vrow1 + c1 * 64 + 32);
      }
      __builtin_amdgcn_s_setprio(1);
#pragma unroll
      for (int ist = 0; ist < 2; ++ist) {
        bf16x8 bp[4];
#pragma unroll
        for (int nt = 0; nt < 4; ++nt)
          bp[nt] = *(const bf16x8*)&PtS[0][PIDX(nt * 16 + ln, ist * 32 + lg * 8)];
#pragma unroll
        for (int nt = 0; nt < 4; ++nt) {
          acc[0][nt] = MFMA16(avA[ist * 2 + 0], bp[nt], acc[0][nt]);
          acc[1][nt] = MFMA16(avA[ist * 2 + 1], bp[nt], acc[1][nt]);
        }
      }
      __builtin_amdgcn_s_setprio(0);
#pragma unroll
      for (int nt = 0; nt < 4; ++nt) {   // pack P(c+1) -> PtS[1]
        float e0 = exp2f(sn[nt][0]), e1 = exp2f(sn[nt][1]), e2 = exp2f(sn[nt][2]), e3 = exp2f(sn[nt][3]);
        lsum[nt] += (e0 + e1) + (e2 + e3);
        uint2v pk; pk[0] = cvtpk(e0, e1); pk[1] = cvtpk(e2, e3);
        *(uint2v*)&PtS[1][PIDX(nt * 16 + ln, w * 16 + lg * 4)] = pk;
      }
      __syncthreads();
      if (pr < 15) {
#pragma unroll
        for (int nt = 0; nt < 4; ++nt) { f32x4 z = {0.f,0.f,0.f,0.f}; sn[nt] = MFMA16(akA, bq[nt], z); }
        int c3 = c + 3, c2 = c + 2;
        akB = *(const bf16x8*)(kTbase + (size_t)c3 * 2048);
        avA[0] = *(const bf16x8*)(Vrow0 + c2 * 64);
        avA[1] = *(const bf16x8*)(Vrow1 + c2 * 64);
        avA[2] = *(const bf16x8*)(Vrow0 + c2 * 64 + 32);
        avA[3] = *(const bf16x8*)(Vrow1 + c2 * 64 + 32);
      }
      __builtin_amdgcn_s_setprio(1);
#pragma unroll
      for (int ist = 0; ist < 2; ++ist) {
        bf16x8 bp[4];
#pragma unroll
        for (int nt = 0; nt < 4; ++nt)
          bp[nt] = *(const bf16x8*)&PtS[1][PIDX(nt * 16 + ln, ist * 32 + lg * 8)];
#pragma unroll
        for (int nt = 0; nt < 4; ++nt) {
          acc[0][nt] = MFMA16(avB[ist * 2 + 0], bp[nt], acc[0][nt]);
          acc[1][nt] = MFMA16(avB[ist * 2 + 1], bp[nt], acc[1][nt]);
        }
      }
      __builtin_amdgcn_s_setprio(0);
      if (pr < 15) {
#pragma unroll
        for (int nt = 0; nt < 4; ++nt) {   // pack P(c+2) -> PtS[0]
          float e0 = exp2f(sn[nt][0]), e1 = exp2f(sn[nt][1]), e2 = exp2f(sn[nt][2]), e3 = exp2f(sn[nt][3]);
          lsum[nt] += (e0 + e1) + (e2 + e3);
          uint2v pk; pk[0] = cvtpk(e0, e1); pk[1] = cvtpk(e2, e3);
          *(uint2v*)&PtS[0][PIDX(nt * 16 + ln, w * 16 + lg * 4)] = pk;
        }
      }
    }
    size_t pb = (((size_t)bg * 16 + jt) * 8 + kc) * 8192;
#pragma unroll
    for (int ct = 0; ct < 2; ++ct)
#pragma unroll
      for (int nt = 0; nt < 4; ++nt)
#pragma unroll
        for (int r = 0; r < 4; ++r)
          pacc[pb + (size_t)(w * 32 + ct * 16 + lg * 4 + r) * 64 + nt * 16 + ln] = acc[ct][nt][r];
#pragma unroll
    for (int nt = 0; nt < 4; ++nt) {
      float v = lsum[nt];
      v += __shfl_xor(v, 16); v += __shfl_xor(v, 32);
      if (lane < 16) redL[w][nt * 16 + lane] = v;
    }
    __syncthreads();
    if (tid < 64)
      pl[(((size_t)bg * 16 + jt) * 8 + kc) * 64 + tid] =
          redL[0][tid] + redL[1][tid] + redL[2][tid] + redL[3][tid];
  } else {
    // ------------------ A_m scores (Eut, lpart) ------------------
    int n2 = n - 512;
    int jt = n2 & 15, ic = (n2 >> 4) & 3, bg = n2 >> 6;
    bf16x8 bq[4];
#pragma unroll
    for (int nt = 0; nt < 4; ++nt) {
      ushort8v t8;
#pragma unroll
      for (int jr = 0; jr < 8; ++jr)
        t8[jr] = qpb[((size_t)bg * 32 + lg * 8 + jr) * NP1 + jt * 64 + nt * 16 + ln];
      bq[nt] = scale_l2e(t8);
    }
    float lsum[4] = {0.f, 0.f, 0.f, 0.f};
    for (int chk = 0; chk < 4; ++chk) {
      int i0 = ic * 256 + chk * 64;
      bf16x8 ak = *(const bf16x8*)(kpt + ((size_t)bg * NP1 + i0 + w * 16 + ln) * 32 + lg * 8);
#pragma unroll
      for (int nt = 0; nt < 4; ++nt) {
        f32x4 z = {0.f, 0.f, 0.f, 0.f};
        f32x4 s = MFMA16(ak, bq[nt], z);
        float e0 = exp2f(s[0]), e1 = exp2f(s[1]), e2 = exp2f(s[2]), e3 = exp2f(s[3]);
        lsum[nt] += (e0 + e1) + (e2 + e3);
        int j = jt * 64 + nt * 16 + ln;
        int ib = i0 + w * 16 + lg * 4;
        uint2v pk;
        pk[0] = cvtpk(e0, e1);
        pk[1] = cvtpk(e2, e3);
        *(uint2v*)(Eut + ((size_t)bg * NP1 + j) * NP1 + ib) = pk;
      }
    }
#pragma unroll
    for (int nt = 0; nt < 4; ++nt) {
      float v = lsum[nt];
      v += __shfl_xor(v, 16); v += __shfl_xor(v, 32);
      if (lane < 16) redL[w][nt * 16 + lane] = v;
    }
    __syncthreads();
    if (tid < 64)
      lpart[((size_t)(bg * 4 + ic)) * NP1 + jt * 64 + tid] =
          redL[0][tid] + redL[1][tid] + redL[2][tid] + redL[3][tid];
  }
}

// ---------------------------------------------------------------------------
// K5: MERGED: blocks [0,2048) = split-K combine -> Yf; blocks [2048,2176) =
// rvec partials (row-parallel) + linv.
// ---------------------------------------------------------------------------
__global__ __launch_bounds__(256) void k_comb2(
    const float* __restrict__ pacc, const float* __restrict__ pl,
    float* __restrict__ Yf, const unsigned short* __restrict__ Eut,
    const float* __restrict__ lpart, float* __restrict__ linv,
    float* __restrict__ rvecp) {
  int n = blockIdx.x, t = threadIdx.x;
  if (n < 2048) {
    int gid = n * 256 + t;   // 524288
    int bg = gid >> 17, rem = gid & 131071;
    int c = rem >> 10, j = rem & 1023;
    int jt = j >> 6, jj = j & 63;
    float s = 0.f, l = 0.f;
#pragma unroll
    for (int kc = 0; kc < 8; ++kc) {
      size_t pb = ((size_t)bg * 16 + jt) * 8 + kc;
      s += pacc[pb * 8192 + c * 64 + jj];
      l += pl[pb * 64 + jj];
    }
    Yf[gid] = s / l;
  } else {
    __shared__ float linv_s[32];
    int n2 = n - 2048;
    int jc = n2 & 31, bg = n2 >> 5;
    if (t < 32) {
      int j = jc * 32 + t;
      float l = lpart[((size_t)(bg * 4 + 0)) * NP1 + j] + lpart[((size_t)(bg * 4 + 1)) * NP1 + j] +
                lpart[((size_t)(bg * 4 + 2)) * NP1 + j] + lpart[((size_t)(bg * 4 + 3)) * NP1 + j];
      float inv = 1.f / l;
      linv_s[t] = inv;
      linv[(size_t)bg * NP1 + j] = inv;
    }
    __syncthreads();
    int i0 = t * 4;
    float a0 = 0.f, a1 = 0.f, a2 = 0.f, a3 = 0.f;
#pragma unroll 8
    for (int jj = 0; jj < 32; ++jj) {
      float li = linv_s[jj];
      ushort4v e4 = *(const ushort4v*)(Eut + ((size_t)bg * NP1 + jc * 32 + jj) * NP1 + i0);
      a0 += b2f(e4[0]) * li; a1 += b2f(e4[1]) * li;
      a2 += b2f(e4[2]) * li; a3 += b2f(e4[3]) * li;
    }
    float4 o = {a0, a1, a2, a3};
    *(float4*)(rvecp + ((size_t)(jc * 4 + bg)) * NP1 + i0) = o;
  }
}

// ---------------------------------------------------------------------------
// K5b: Perron deflation: c_row=(y.r)/(1.r); Yf := Y-c/2, U0b := bf16(Y-c).
// grid (ct 16, bg 4)
// ---------------------------------------------------------------------------
__global__ __launch_bounds__(256) void k_proj(
    const float* __restrict__ rvecp, float* __restrict__ Yf,
    unsigned short* __restrict__ U0b) {
  int ct = blockIdx.x, bg = blockIdx.y, t = threadIdx.x;
  __shared__ float rs[1024];
  __shared__ float red[256];
  __shared__ float crow[8];
  __shared__ float sSs;
  for (int j = t; j < 1024; j += 256) {
    float s = 0.f;
#pragma unroll
    for (int p = 0; p < 32; ++p) s += rvecp[((size_t)(p * 4 + bg)) * NP1 + j];
    rs[j] = s;
  }
  __syncthreads();
  float p = rs[t] + rs[t + 256] + rs[t + 512] + rs[t + 768];
  red[t] = p; __syncthreads();
  for (int s = 128; s > 0; s >>= 1) {
    if (t < s) red[t] += red[t + s];
    __syncthreads();
  }
  if (t == 0) sSs = red[0];
  __syncthreads();
  int row = t >> 5, ln32 = t & 31;
  const float* yrow = Yf + ((size_t)(bg * 128 + ct * 8 + row)) * NP1;
  float a = 0.f;
  for (int j = ln32; j < 1024; j += 32) a += yrow[j] * rs[j];
#pragma unroll
  for (int m = 1; m <= 16; m <<= 1) a += __shfl_xor(a, m, 32);
  if (ln32 == 0) crow[row] = a / sSs;
  __syncthreads();
  for (int e = t; e < 8 * 1024; e += 256) {
    int rr = e >> 10, j = e & 1023;
    size_t o = ((size_t)(bg * 128 + ct * 8 + rr)) * NP1 + j;
    float y = Yf[o], cv = crow[rr];
    Yf[o] = y - 0.5f * cv;
    U0b[o] = f2bu(y - cv);
  }
}

// ---------------------------------------------------------------------------
// K6: single Neumann step: W2b = bf16(Yf - (U0 . Eut)*linv[j])
// grid (jt 32, ct 2, bg 4)
// ---------------------------------------------------------------------------
__global__ __launch_bounds__(256) void k_neu(
    const unsigned short* __restrict__ Vin, const unsigned short* __restrict__ Eut,
    const float* __restrict__ linv, const float* __restrict__ W2f,
    unsigned short* __restrict__ W2b) {
  int jt = blockIdx.x, ct = blockIdx.y, bg = blockIdx.z;
  int tid = threadIdx.x, w = tid >> 6, lane = tid & 63;
  int lg = lane >> 4, ln = lane & 15;
  int j0 = jt * 32, c0 = ct * 64 + w * 16;
  f32x4 acc[2] = {};
  for (int ks = 0; ks < 32; ++ks) {
    int i0 = ks * 32;
    bf16x8 a = *(const bf16x8*)(Vin + ((size_t)(bg * 128) + c0 + ln) * NP1 + i0 + lg * 8);
#pragma unroll
    for (int nt = 0; nt < 2; ++nt) {
      bf16x8 bt = *(const bf16x8*)(Eut + ((size_t)bg * NP1 + j0 + nt * 16 + ln) * NP1 + i0 + lg * 8);
      acc[nt] = MFMA16(a, bt, acc[nt]);
    }
  }
#pragma unroll
  for (int nt = 0; nt < 2; ++nt) {
    int j = j0 + nt * 16 + ln;
    float li = linv[(size_t)bg * NP1 + j];
#pragma unroll
    for (int r = 0; r < 4; ++r) {
      size_t o = ((size_t)(bg * 128) + c0 + lg * 4 + r) * NP1 + j;
      W2b[o] = f2bu(W2f[o] - acc[nt][r] * li);
    }
  }
}

// ---------------------------------------------------------------------------
// K7: flash O = W2 @ exp(k^T Qf)/l + W2[:,i1(j)]   (full M^-1 in W2)
// grid (jt 256, bg 4); register-prefetched pipeline; VALU lsum
// ---------------------------------------------------------------------------
__global__ __launch_bounds__(256) void k_flashO(
    const unsigned short* __restrict__ qkvb, const unsigned short* __restrict__ kpt,
    const unsigned short* __restrict__ W2b, unsigned short* __restrict__ Ot) {
  int jt = blockIdx.x, bg = blockIdx.y;
  int b = bg >> 1, g = bg & 1;
  int tid = threadIdx.x, w = tid >> 6, lane = tid & 63;
  int lg = lane >> 4, ln = lane & 15;
  __shared__ unsigned short PtS[2][64 * 64];
  __shared__ float redL[4][64];
  __shared__ float smL[64];
  const int Qch = b * 384 + g * 32;
  bf16x8 bq[4];
#pragma unroll
  for (int nt = 0; nt < 4; ++nt) {
    ushort8v t8;
#pragma unroll
    for (int jr = 0; jr < 8; ++jr)
      t8[jr] = qkvb[(size_t)(Qch + lg * 8 + jr) * HWN + jt * 64 + nt * 16 + ln];
    bq[nt] = scale_l2e(t8);
  }
  f32x4 acc[2][4] = {};
  float lsum[4] = {0.f, 0.f, 0.f, 0.f};
  const unsigned short* kbase = kpt + ((size_t)bg * NP1 + w * 16 + ln) * 32 + lg * 8;   // chunk stride 2048
  const unsigned short* Wrow0 = W2b + ((size_t)bg * 128 + w * 32 + ln) * NP1 + lg * 8;
  const unsigned short* Wrow1 = W2b + ((size_t)bg * 128 + w * 32 + 16 + ln) * NP1 + lg * 8;

  bf16x8 akA, akB;
  bf16x8 avA[4], avB[4];
  akA = *(const bf16x8*)(kbase);
  {
    f32x4 sn[4];
#pragma unroll
    for (int nt = 0; nt < 4; ++nt) { f32x4 z = {0.f,0.f,0.f,0.f}; sn[nt] = MFMA16(akA, bq[nt], z); }
    akB = *(const bf16x8*)(kbase + 2048);
    avA[0] = *(const bf16x8*)(Wrow0);
    avA[1] = *(const bf16x8*)(Wrow1);
    avA[2] = *(const bf16x8*)(Wrow0 + 32);
    avA[3] = *(const bf16x8*)(Wrow1 + 32);
#pragma unroll
    for (int nt = 0; nt < 4; ++nt) {
      float e0 = exp2f(sn[nt][0]), e1 = exp2f(sn[nt][1]), e2 = exp2f(sn[nt][2]), e3 = exp2f(sn[nt][3]);
      lsum[nt] += (e0 + e1) + (e2 + e3);
      uint2v pk; pk[0] = cvtpk(e0, e1); pk[1] = cvtpk(e2, e3);
      *(uint2v*)&PtS[0][PIDX(nt * 16 + ln, w * 16 + lg * 4)] = pk;
    }
  }
  for (int pr = 0; pr < 8; ++pr) {
    int c = pr * 2;
    __syncthreads();
    f32x4 sn[4];
#pragma unroll
    for (int nt = 0; nt < 4; ++nt) { f32x4 z = {0.f,0.f,0.f,0.f}; sn[nt] = MFMA16(akB, bq[nt], z); }
    {
      int c2 = (c + 2) & 15, c1 = c + 1;
      akA = *(const bf16x8*)(kbase + (size_t)c2 * 2048);
      avB[0] = *(const bf16x8*)(Wrow0 + c1 * 64);
      avB[1] = *(const bf16x8*)(Wrow1 + c1 * 64);
      avB[2] = *(const bf16x8*)(Wrow0 + c1 * 64 + 32);
      avB[3] = *(const bf16x8*)(Wrow1 + c1 * 64 + 32);
    }
    __builtin_amdgcn_s_setprio(1);
#pragma unroll
    for (int ist = 0; ist < 2; ++ist) {
      bf16x8 bp[4];
#pragma unroll
      for (int nt = 0; nt < 4; ++nt)
        bp[nt] = *(const bf16x8*)&PtS[0][PIDX(nt * 16 + ln, ist * 32 + lg * 8)];
#pragma unroll
      for (int nt = 0; nt < 4; ++nt) {
        acc[0][nt] = MFMA16(avA[ist * 2 + 0], bp[nt], acc[0][nt]);
        acc[1][nt] = MFMA16(avA[ist * 2 + 1], bp[nt], acc[1][nt]);
      }
    }
    __builtin_amdgcn_s_setprio(0);
#pragma unroll
    for (int nt = 0; nt < 4; ++nt) {   // pack P(c+1) -> PtS[1]
      float e0 = exp2f(sn[nt][0]), e1 = exp2f(sn[nt][1]), e2 = exp2f(sn[nt][2]), e3 = exp2f(sn[nt][3]);
      lsum[nt] += (e0 + e1) + (e2 + e3);
      uint2v pk; pk[0] = cvtpk(e0, e1); pk[1] = cvtpk(e2, e3);
      *(uint2v*)&PtS[1][PIDX(nt * 16 + ln, w * 16 + lg * 4)] = pk;
    }
    __syncthreads();
    if (pr < 7) {
#pragma unroll
      for (int nt = 0; nt < 4; ++nt) { f32x4 z = {0.f,0.f,0.f,0.f}; sn[nt] = MFMA16(akA, bq[nt], z); }
      int c3 = c + 3, c2 = c + 2;
      akB = *(const bf16x8*)(kbase + (size_t)c3 * 2048);
      avA[0] = *(const bf16x8*)(Wrow0 + c2 * 64);
      avA[1] = *(const bf16x8*)(Wrow1 + c2 * 64);
      avA[2] = *(const bf16x8*)(Wrow0 + c2 * 64 + 32);
      avA[3] = *(const bf16x8*)(Wrow1 + c2 * 64 + 32);
    }
    __builtin_amdgcn_s_setprio(1);
#pragma unroll
    for (int ist = 0; ist < 2; ++ist) {
      bf16x8 bp[4];
#pragma unroll
      for (int nt = 0; nt < 4; ++nt)
        bp[nt] = *(const bf16x8*)&PtS[1][PIDX(nt * 16 + ln, ist * 32 + lg * 8)];
#pragma unroll
      for (int nt = 0; nt < 4; ++nt) {
        acc[0][nt] = MFMA16(avB[ist * 2 + 0], bp[nt], acc[0][nt]);
        acc[1][nt] = MFMA16(avB[ist * 2 + 1], bp[nt], acc[1][nt]);
      }
    }
    __builtin_amdgcn_s_setprio(0);
    if (pr < 7) {
#pragma unroll
      for (int nt = 0; nt < 4; ++nt) {   // pack P(c+2) -> PtS[0]
        float e0 = exp2f(sn[nt][0]), e1 = exp2f(sn[nt][1]), e2 = exp2f(sn[nt][2]), e3 = exp2f(sn[nt][3]);
        lsum[nt] += (e0 + e1) + (e2 + e3);
        uint2v pk; pk[0] = cvtpk(e0, e1); pk[1] = cvtpk(e2, e3);
        *(uint2v*)&PtS[0][PIDX(nt * 16 + ln, w * 16 + lg * 4)] = pk;
      }
    }
  }
#pragma unroll
  for (int nt = 0; nt < 4; ++nt) {
    float v = lsum[nt];
    v += __shfl_xor(v, 16); v += __shfl_xor(v, 32);
    if (lane < 16) redL[w][nt * 16 + lane] = v;
  }
  __syncthreads();
  if (tid < 64) smL[tid] = redL[0][tid] + redL[1][tid] + redL[2][tid] + redL[3][tid];
  __syncthreads();
#pragma unroll
  for (int nt = 0; nt < 4; ++nt) {
    int jj = nt * 16 + ln;
    int jg = jt * 64 + jj;
    float li = 1.f / smL[jj];
    int i1 = (jg >> 9) * 32 + ((jg & 127) >> 2);
#pragma unroll
    for (int ct = 0; ct < 2; ++ct) {
      int c = w * 32 + ct * 16 + lg * 4;
      float v0 = acc[ct][nt][0] * li + b2f(W2b[((size_t)bg * 128 + c + 0) * NP1 + i1]);
      float v1 = acc[ct][nt][1] * li + b2f(W2b[((size_t)bg * 128 + c + 1) * NP1 + i1]);
      float v2 = acc[ct][nt][2] * li + b2f(W2b[((size_t)bg * 128 + c + 2) * NP1 + i1]);
      float v3 = acc[ct][nt][3] * li + b2f(W2b[((size_t)bg * 128 + c + 3) * NP1 + i1]);
      uint2v o2; o2[0] = cvtpk(v0, v1); o2[1] = cvtpk(v2, v3);
      *(uint2v*)(Ot + ((size_t)b * HWN + jg) * 256 + g * 128 + c) = o2;
    }
  }
}

// ---------------------------------------------------------------------------
// K8: out GEMM, ALL 4 o-tiles (256 rows) per block; residual from xbT (bf16).
// grid (pt 256, b 2)
// ---------------------------------------------------------------------------
__global__ __launch_bounds__(256) void k_out(
    const unsigned short* __restrict__ wob, const unsigned short* __restrict__ Ot,
    const float* __restrict__ out_b, const unsigned short* __restrict__ xbT,
    const float* __restrict__ gamma, const int* __restrict__ mode,
    float* __restrict__ out) {
  int pt = blockIdx.x, b = blockIdx.y;
  int tid = threadIdx.x, w = tid >> 6, lane = tid & 63;
  int lg = lane >> 4, ln = lane & 15;
  f32x4 acc[4][4] = {};
#pragma unroll
  for (int ks = 0; ks < 8; ++ks) {
    int c0 = ks * 32;
    bf16x8 bx[4];
#pragma unroll
    for (int nt = 0; nt < 4; ++nt)
      bx[nt] = *(const bf16x8*)(Ot + ((size_t)b * HWN + pt * 64 + nt * 16 + ln) * 256 + c0 + lg * 8);
#pragma unroll
    for (int h = 0; h < 4; ++h) {
      bf16x8 aw = *(const bf16x8*)(wob + (size_t)(h * 64 + w * 16 + ln) * 256 + c0 + lg * 8);
#pragma unroll
      for (int nt = 0; nt < 4; ++nt)
        acc[h][nt] = MFMA16(aw, bx[nt], acc[h][nt]);
    }
  }
  float gm = gamma[0];
  int md = mode[0];
#pragma unroll
  for (int h = 0; h < 4; ++h) {
    int o0 = h * 64 + w * 16 + lg * 4;
    float b0 = out_b[o0], b1 = out_b[o0 + 1], b2 = out_b[o0 + 2], b3 = out_b[o0 + 3];
#pragma unroll
    for (int nt = 0; nt < 4; ++nt) {
      int p = pt * 64 + nt * 16 + ln;
      ushort4v xr = *(const ushort4v*)(xbT + ((size_t)b * HWN + p) * 256 + o0);
      float v0 = acc[h][nt][0] + b0, v1 = acc[h][nt][1] + b1;
      float v2 = acc[h][nt][2] + b2, v3 = acc[h][nt][3] + b3;
      size_t off = ((size_t)b * 256 + o0) * HWN + p;
      if (md == 0) {
        out[off]           = gm * v0 + b2f(xr[0]);
        out[off + HWN]     = gm * v1 + b2f(xr[1]);
        out[off + 2 * HWN] = gm * v2 + b2f(xr[2]);
        out[off + 3 * HWN] = gm * v3 + b2f(xr[3]);
      } else {
        out[off]           = v0;
        out[off + HWN]     = v1;
        out[off + 2 * HWN] = v2;
        out[off + 3 * HWN] = v3;
      }
    }
  }
}

// ---------------------------------------------------------------------------
extern "C" void kernel_launch(void* const* d_in, const int* in_sizes, int n_in,
                              void* d_out, int out_size, void* d_ws, size_t ws_size,
                              hipStream_t stream) {
  (void)in_sizes; (void)n_in; (void)out_size;
  const float* x     = (const float*)d_in[0];
  const float* qkv_w = (const float*)d_in[1];
  const float* qkv_b = (const float*)d_in[2];
  const float* out_w = (const float*)d_in[3];
  const float* out_b = (const float*)d_in[4];
  const float* gamma = (const float*)d_in[5];
  const int*   mode  = (const int*)d_in[6];
  float* out = (float*)d_out;

  char* wsb = (char*)d_ws;
  size_t off = 0;
  auto alloc = [&](size_t bytes) { char* p = wsb + off; off += bytes; return p; };
  unsigned short* xbT  = (unsigned short*)alloc(16777216);  // [2][16384][256]
  unsigned short* wqb  = (unsigned short*)alloc(196608);
  unsigned short* wob  = (unsigned short*)alloc(131072);
  unsigned short* qkvb = (unsigned short*)alloc(25165824);  // [2][384][16384]
  unsigned short* kT   = (unsigned short*)alloc(4194304);   // [4][16384][32]
  unsigned short* qpb  = (unsigned short*)alloc(262144);    // [4][32][1024]
  unsigned short* kpt  = (unsigned short*)alloc(262144);    // [4][1024][32]
  unsigned short* Eut  = (unsigned short*)alloc(8388608);   // [4][1024 j][1024 i]
  float*          lpart= (float*)alloc(65536);              // [4][4][1024]
  float*          linv = (float*)alloc(16384);              // [4][1024]
  float*          rvecp= (float*)alloc(524288);             // [32][4][1024]
  float*          pacc = (float*)alloc(16777216);           // [4][16][8][128][64]
  float*          pl   = (float*)alloc(131072);             // [4][16][8][64]
  float*          Yf   = (float*)alloc(2097152);            // [4][128][1024]
  unsigned short* U0b  = (unsigned short*)alloc(1048576);
  unsigned short* W2b  = (unsigned short*)alloc(1048576);
  unsigned short* Ot   = (unsigned short*)pacc;             // alias: pacc dead after k_comb2
  if (ws_size < off) return;   // ~76.5 MB

  k_cast<<<2208, 256, 0, stream>>>(x, qkv_w, out_w, xbT, wqb, wob);
  k_qkv<<<dim3(256, 2), 256, 0, stream>>>(wqb, xbT, qkv_b, qkvb, kT);
  k_pool<<<512, 256, 0, stream>>>(qkvb, qpb, kpt);
  k_fw1s<<<768, 256, 0, stream>>>(qkvb, kT, qpb, kpt, pacc, pl, Eut, lpart);
  k_comb2<<<2176, 256, 0, stream>>>(pacc, pl, Yf, Eut, lpart, linv, rvecp);
  k_proj<<<dim3(16, 4), 256, 0, stream>>>(rvecp, Yf, U0b);
  k_neu<<<dim3(32, 2, 4), 256, 0, stream>>>(U0b, Eut, linv, Yf, W2b);
  k_flashO<<<dim3(256, 4), 256, 0, stream>>>(qkvb, kpt, W2b, Ot);
  k_out<<<dim3(256, 2), 256, 0, stream>>>(wob, Ot, out_b, xbT, gamma, mode, out);
}